// Round 15
// baseline (211.238 us; speedup 1.0000x reference)
//
#include <hip/hip_runtime.h>

// Problem constants
#define BSZ 16
#define NN  128
#define HH  256
#define LLG 9
#define FFE 48   // edge feature dim (padded to 64 for MFMA K)

typedef float        f32x4 __attribute__((ext_vector_type(4)));
typedef _Float16     f16x8 __attribute__((ext_vector_type(8)));
typedef unsigned int u32x4 __attribute__((ext_vector_type(4)));

static __device__ __forceinline__ unsigned short f2h_bits(float x) {
    _Float16 h = (_Float16)x;   // RNE
    return __builtin_bit_cast(unsigned short, h);
}

static __device__ __forceinline__ float fast_silu(float x) {
    float e = __builtin_amdgcn_exp2f(x * -1.44269504088896341f);
    return x * __builtin_amdgcn_rcpf(1.0f + e);
}

// ---------------------------------------------------------------------------
// Kernel 1: weight prep (R14 verbatim). Grid 784.
// ---------------------------------------------------------------------------
__global__ __launch_bounds__(256) void pre_w(
    const float* __restrict__ W1, const float* __restrict__ W2,
    const float* __restrict__ graph, const float* __restrict__ b1,
    unsigned short* __restrict__ W2T, unsigned short* __restrict__ WeT,
    unsigned short* __restrict__ W1jiT, float* __restrict__ pg)
{
    const int blk = blockIdx.x;
    const int t   = threadIdx.x;
    if (blk < 256) {
        int tid = blk * 256 + t;
        int ho = tid >> 8, k = tid & 255;
        W2T[(ho << 8) + k] = f2h_bits(W2[(k << 8) + ho]);
        if (tid < 256 * 64) {
            int h = tid >> 6, f = tid & 63;
            WeT[(h << 6) + f] = (f < FFE) ? f2h_bits(W1[(521 + f) * HH + h])
                                          : (unsigned short)0;
        }
    } else if (blk < 768) {
        int tid = (blk - 256) * 256 + t;      // 0..131071
        int hp = tid >> 8, f = tid & 255;     // h' 0..511, f 0..255
        int src = (((hp >> 8) << 8) + f) * HH + (hp & 255);
        W1jiT[(hp << 8) + f] = f2h_bits(W1[src]);
    } else {
        int b = blk - 768;                    // 0..15
        float acc = b1[t];
        #pragma unroll
        for (int l = 0; l < LLG; ++l)
            acc = fmaf(graph[b * LLG + l], W1[(2 * HH + l) * HH + t], acc);
        pg[(b << 8) + t] = acc;
    }
}

// ---------------------------------------------------------------------------
// Kernel 2: pj/base via MFMA (R14 verbatim). Grid 64.
// ---------------------------------------------------------------------------
__global__ __launch_bounds__(256) void pre_pjbase_mfma(
    const float* __restrict__ node, const unsigned short* __restrict__ W1jiT,
    const float* __restrict__ pg,
    float* __restrict__ pj, float* __restrict__ base)
{
    __shared__ unsigned char nls[32 * 512];   // 16 KB: node[r][f] f16, swizzled
    const int tid = threadIdx.x;
    const int w    = tid >> 6;
    const int lane = tid & 63;
    const int q    = lane >> 4;
    const int c    = lane & 15;
    const int b  = blockIdx.x >> 2;
    const int r0 = (blockIdx.x & 3) << 5;
    const unsigned ck = (unsigned)(c & 7) << 4;

    const float* nb = node + (((size_t)b << 7) + r0) * HH;
    #pragma unroll
    for (int p = 0; p < 8; ++p) {
        const int e4 = (p << 8) + tid;        // float4 idx < 2048
        const int r  = e4 >> 6, f4 = e4 & 63;
        const f32x4 x = *reinterpret_cast<const f32x4*>(nb + (e4 << 2));
        unsigned int lo = __builtin_bit_cast(unsigned int,
                            __builtin_amdgcn_cvt_pkrtz(x[0], x[1]));
        unsigned int hi = __builtin_bit_cast(unsigned int,
                            __builtin_amdgcn_cvt_pkrtz(x[2], x[3]));
        const unsigned off = (unsigned)(r << 9) +
            (((unsigned)(f4 << 3)) ^ ((unsigned)(r & 7) << 4));
        *reinterpret_cast<uint2*>(&nls[off]) = make_uint2(lo, hi);
    }
    __syncthreads();

    const int wh = w << 7;                    // h'-slice base
    f32x4 acc[8][2];
    #pragma unroll
    for (int mt = 0; mt < 8; ++mt)
        #pragma unroll
        for (int nt = 0; nt < 2; ++nt) acc[mt][nt] = f32x4{0.f, 0.f, 0.f, 0.f};

    #pragma unroll 2
    for (int kk = 0; kk < 8; ++kk) {
        const unsigned kb = (unsigned)((kk << 6) + (q << 4));
        f16x8 bfr[2];
        #pragma unroll
        for (int nt = 0; nt < 2; ++nt) {
            const int r = (nt << 4) + c;
            bfr[nt] = *reinterpret_cast<const f16x8*>(
                &nls[(unsigned)(r << 9) + (kb ^ ck)]);
        }
        #pragma unroll
        for (int mt = 0; mt < 8; ++mt) {
            const f16x8 af = *reinterpret_cast<const f16x8*>(
                W1jiT + ((wh + (mt << 4) + c) << 8) + (kk << 5) + (q << 3));
            #pragma unroll
            for (int nt = 0; nt < 2; ++nt)
                acc[mt][nt] = __builtin_amdgcn_mfma_f32_16x16x32_f16(
                    af, bfr[nt], acc[mt][nt], 0, 0, 0);
        }
    }

    if (w < 2) {
        #pragma unroll
        for (int mt = 0; mt < 8; ++mt) {
            const int hb = wh + (mt << 4) + (q << 2);
            #pragma unroll
            for (int nt = 0; nt < 2; ++nt) {
                const int r = r0 + (nt << 4) + c;
                *reinterpret_cast<f32x4*>(
                    pj + (((size_t)b << 7) + r) * HH + hb) = acc[mt][nt];
            }
        }
    } else {
        #pragma unroll
        for (int mt = 0; mt < 8; ++mt) {
            const int hb = wh - 256 + (mt << 4) + (q << 2);
            const f32x4 pgv = *reinterpret_cast<const f32x4*>(
                pg + (b << 8) + hb);
            #pragma unroll
            for (int nt = 0; nt < 2; ++nt) {
                const int r = r0 + (nt << 4) + c;
                *reinterpret_cast<f32x4*>(
                    base + (((size_t)b << 7) + r) * HH + hb) = acc[mt][nt] + pgv;
            }
        }
    }
}

// ---------------------------------------------------------------------------
// Kernel 3: fused main — j-chunked (2x64) at 40 KB LDS with
// __launch_bounds__(512, 6): unified regs capped at 85 -> 6 waves/SIMD ->
// THREE 8-wave blocks/CU (24 waves, +50% vs R5's 16). R7 proved the chunked
// algebra but sat at 92 unified regs = 5 waves/SIMD, which rounds down to
// 2 blocks at 8-wave granularity -> no occupancy gain. This round closes
// that 7-reg gap. Chunk-1 staging placed right after bar2 so its global
// loads overlap GEMM2(0) (compiler-scheduled; no long-held regs).
// ---------------------------------------------------------------------------
__global__ __launch_bounds__(512, 6) void fused_msg(
    const float* __restrict__ edge, const float* __restrict__ pj,
    const float* __restrict__ base, const unsigned short* __restrict__ W2T,
    const unsigned short* __restrict__ WeT, const float* __restrict__ b2,
    float* __restrict__ out)
{
    __shared__ unsigned char h1s[64 * HH * 2];   // 32 KB: h1[jc][h] f16, swizzled
    __shared__ unsigned char efs[64 * 64 * 2];   //  8 KB: edge[jc][f] f16, padded+swizzled
    const int tid  = threadIdx.x;
    const int w    = tid >> 6;         // wave 0..7
    const int lane = tid & 63;
    const int q    = lane >> 4;        // quad 0..3
    const int c    = lane & 15;
    // T1: XCD-chunked swizzle (2048 blocks, 8 XCDs, bijective)
    const int g    = blockIdx.x;
    const int bi   = ((g & 7) << 8) + (g >> 3);   // b*128 + i
    const int b    = bi >> 7;

    const float* eb = edge + (size_t)bi * (NN * FFE);

    float b2v[2];
    #pragma unroll
    for (int nt = 0; nt < 2; ++nt) b2v[nt] = b2[(w << 5) + (nt << 4) + c];
    float s[2] = {0.f, 0.f};

    // convert one float4 of edge to f16 and write to swizzled efs slot
    auto stage_write = [&](f32x4 x, int e4) {
        const int j  = e4 / 12;                  // 12 float4 per 48-float row
        const int f4 = e4 - j * 12;              // 0..11
        unsigned int lo = __builtin_bit_cast(unsigned int,
                            __builtin_amdgcn_cvt_pkrtz(x[0], x[1]));
        unsigned int hi = __builtin_bit_cast(unsigned int,
                            __builtin_amdgcn_cvt_pkrtz(x[2], x[3]));
        const unsigned int off = (unsigned)(j << 7) +
            (((unsigned)(f4 << 3)) ^ ((unsigned)(j & 7) << 4));
        *reinterpret_cast<uint2*>(&efs[off]) = make_uint2(lo, hi);
    };
    auto stage_chunk = [&](int chunk) {
        const float* cb = eb + chunk * 3072;
        f32x4 xa = *reinterpret_cast<const f32x4*>(cb + (tid << 2));
        stage_write(xa, tid);
        if (tid < 256) {
            f32x4 xb = *reinterpret_cast<const f32x4*>(cb + ((512 + tid) << 2));
            stage_write(xb, 512 + tid);
        }
    };

    // zero-fill padded f in [48,64) once
    if (tid < 256) {
        const int j = tid >> 2, gg = tid & 3;
        const unsigned int off = (unsigned)(j << 7) +
            (((unsigned)(96 + (gg << 3))) ^ ((unsigned)(j & 7) << 4));
        *reinterpret_cast<uint2*>(&efs[off]) = make_uint2(0u, 0u);
    }

    // GEMM1 + epilogue1 for one chunk: D1[h(32), jc(64)] -> silu -> h1s
    auto gemm1 = [&](int chunk) {
        f32x4 acc1[2][4];
        #pragma unroll
        for (int mt = 0; mt < 2; ++mt)
            #pragma unroll
            for (int nt = 0; nt < 4; ++nt) acc1[mt][nt] = f32x4{0.f, 0.f, 0.f, 0.f};

        #pragma unroll
        for (int kk = 0; kk < 2; ++kk) {
            const int koff = (kk << 5) + (q << 3);   // f16-units f offset
            const int fb   = koff << 1;              // byte offset in efs row
            f16x8 af[2];
            #pragma unroll
            for (int mt = 0; mt < 2; ++mt) {
                const int row = (w << 5) + (mt << 4) + c;       // h
                af[mt] = *reinterpret_cast<const f16x8*>(WeT + (row << 6) + koff);
            }
            #pragma unroll
            for (int nt = 0; nt < 4; ++nt) {
                const int j = (nt << 4) + c;                    // local jc
                const f16x8 bf = *reinterpret_cast<const f16x8*>(
                    &efs[(unsigned)(j << 7) +
                         (((unsigned)fb) ^ ((unsigned)(j & 7) << 4))]);
                #pragma unroll
                for (int mt = 0; mt < 2; ++mt)
                    acc1[mt][nt] = __builtin_amdgcn_mfma_f32_16x16x32_f16(
                        af[mt], bf, acc1[mt][nt], 0, 0, 0);
            }
        }

        #pragma unroll
        for (int mt = 0; mt < 2; ++mt) {
            const int h0 = (w << 5) + (mt << 4) + (q << 2);
            const f32x4 bb = *reinterpret_cast<const f32x4*>(
                base + ((size_t)bi << 8) + h0);
            #pragma unroll
            for (int nt = 0; nt < 4; ++nt) {
                const int jc = (nt << 4) + c;
                const int jg = (chunk << 6) + jc;
                const f32x4 pjv = *reinterpret_cast<const f32x4*>(
                    pj + (((size_t)b << 7) + jg) * HH + h0);
                float s0 = fast_silu(acc1[mt][nt][0] + bb[0] + pjv[0]);
                float s1 = fast_silu(acc1[mt][nt][1] + bb[1] + pjv[1]);
                float s2 = fast_silu(acc1[mt][nt][2] + bb[2] + pjv[2]);
                float s3 = fast_silu(acc1[mt][nt][3] + bb[3] + pjv[3]);
                unsigned int lo = __builtin_bit_cast(unsigned int,
                                    __builtin_amdgcn_cvt_pkrtz(s0, s1));
                unsigned int hi = __builtin_bit_cast(unsigned int,
                                    __builtin_amdgcn_cvt_pkrtz(s2, s3));
                const unsigned int off = (unsigned)(jc << 9) +
                    (((unsigned)(h0 << 1)) ^ ((unsigned)(jc & 7) << 4));
                *reinterpret_cast<uint2*>(&h1s[off]) = make_uint2(lo, hi);
            }
        }
    };

    // GEMM2 for one chunk: D2[jc(64), ho(32)]; silu + partial sums into s[]
    auto gemm2 = [&]() {
        f32x4 acc2[4][2];
        #pragma unroll
        for (int m = 0; m < 4; ++m)
            #pragma unroll
            for (int nt = 0; nt < 2; ++nt) acc2[m][nt] = f32x4{0.f, 0.f, 0.f, 0.f};

        const unsigned short* wp0 = W2T + (((w << 5) + c) << 8) + (q << 3);
        const unsigned short* wp1 = wp0 + (16 << 8);

        #pragma unroll 2
        for (int kk = 0; kk < 8; ++kk) {
            const f16x8 bw0 = *reinterpret_cast<const f16x8*>(wp0 + (kk << 5));
            const f16x8 bw1 = *reinterpret_cast<const f16x8*>(wp1 + (kk << 5));
            const int kb = (kk << 6) + (q << 4);     // byte offset of k-slice
            f16x8 a2[4];
            #pragma unroll
            for (int m = 0; m < 4; ++m) {
                const int jc = (m << 4) + c;
                const unsigned int off = (unsigned)(jc << 9) +
                    (((unsigned)kb) ^ ((unsigned)(jc & 7) << 4));
                a2[m] = *reinterpret_cast<const f16x8*>(&h1s[off]);
            }
            #pragma unroll
            for (int m = 0; m < 4; ++m) {
                acc2[m][0] = __builtin_amdgcn_mfma_f32_16x16x32_f16(
                    a2[m], bw0, acc2[m][0], 0, 0, 0);
                acc2[m][1] = __builtin_amdgcn_mfma_f32_16x16x32_f16(
                    a2[m], bw1, acc2[m][1], 0, 0, 0);
            }
        }

        #pragma unroll
        for (int nt = 0; nt < 2; ++nt)
            #pragma unroll
            for (int m = 0; m < 4; ++m)
                #pragma unroll
                for (int r = 0; r < 4; ++r)
                    s[nt] += fast_silu(acc2[m][nt][r] + b2v[nt]);
    };

    // ---- chunk 0 ----
    stage_chunk(0);
    __syncthreads();   // bar1: efs(0) ready
    gemm1(0);
    __syncthreads();   // bar2: h1s(0) ready, efs(0) consumed
    stage_chunk(1);    // efs(1) writes: safe (all waves past gemm1(0) reads);
                       // global loads overlap gemm2(0)'s MFMAs below
    gemm2();
    __syncthreads();   // bar3: efs(1) ready, gemm2(0) done in all waves
    // ---- chunk 1 ----
    gemm1(1);
    __syncthreads();   // bar4: h1s(1) ready
    gemm2();

    // butterfly across quads, store
    #pragma unroll
    for (int nt = 0; nt < 2; ++nt) {
        s[nt] += __shfl_xor(s[nt], 16);
        s[nt] += __shfl_xor(s[nt], 32);
    }
    if (q < 2)
        out[((size_t)bi << 8) + (w << 5) + (q << 4) + c] = s[q] * 0.0078125f;
}

// ---------------------------------------------------------------------------
extern "C" void kernel_launch(void* const* d_in, const int* in_sizes, int n_in,
                              void* d_out, int out_size, void* d_ws, size_t ws_size,
                              hipStream_t stream)
{
    const float* node  = (const float*)d_in[0];
    const float* edge  = (const float*)d_in[1];
    const float* graph = (const float*)d_in[2];
    const float* W1    = (const float*)d_in[3];
    const float* b1    = (const float*)d_in[4];
    const float* W2    = (const float*)d_in[5];
    const float* b2    = (const float*)d_in[6];
    float* out = (float*)d_out;

    char* ws = (char*)d_ws;
    unsigned short* W2T   = (unsigned short*)ws;               // 131072 B
    unsigned short* WeT   = (unsigned short*)(ws + 131072);    //  32768 B
    unsigned short* W1jiT = (unsigned short*)(ws + 163840);    // 262144 B
    float* pg   = (float*)(ws + 425984);                       //  16384 B
    float* pj   = (float*)(ws + 442368);                       // 2 MB
    float* base = (float*)(ws + 442368 + 2097152);             // 2 MB

    pre_w          <<<784, 256, 0, stream>>>(W1, W2, graph, b1, W2T, WeT, W1jiT, pg);
    pre_pjbase_mfma<<< 64, 256, 0, stream>>>(node, W1jiT, pg, pj, base);
    fused_msg      <<<BSZ * NN, 512, 0, stream>>>(edge, pj, base, W2T, WeT, b2, out);
}

// Round 16
// 100.109 us; speedup vs baseline: 2.1101x; 2.1101x over previous
//
#include <hip/hip_runtime.h>

// Problem constants
#define BSZ 16
#define NN  128
#define HH  256
#define LLG 9
#define FFE 48   // edge feature dim (padded to 64 for MFMA K)

typedef float        f32x4 __attribute__((ext_vector_type(4)));
typedef _Float16     f16x8 __attribute__((ext_vector_type(8)));
typedef unsigned int u32x4 __attribute__((ext_vector_type(4)));

static __device__ __forceinline__ unsigned short f2h_bits(float x) {
    _Float16 h = (_Float16)x;   // RNE
    return __builtin_bit_cast(unsigned short, h);
}

static __device__ __forceinline__ float fast_silu(float x) {
    float e = __builtin_amdgcn_exp2f(x * -1.44269504088896341f);
    return x * __builtin_amdgcn_rcpf(1.0f + e);
}

// ---------------------------------------------------------------------------
// Kernel 1: weight prep. Grid 784.
//   blk 0..255 : W2T[ho][k] (256x256 f16)  + WeT[h][f] (256x64 f16, padded)
//   blk 256..767: W1jiT[h'][f] (512x256 f16) = W1[f + 256*(h'>=256)][h'&255]
//   blk 768..783: pg[b][h] = b1[h] + graph[b]@Wg   (16x256 f32)
// ---------------------------------------------------------------------------
__global__ __launch_bounds__(256) void pre_w(
    const float* __restrict__ W1, const float* __restrict__ W2,
    const float* __restrict__ graph, const float* __restrict__ b1,
    unsigned short* __restrict__ W2T, unsigned short* __restrict__ WeT,
    unsigned short* __restrict__ W1jiT, float* __restrict__ pg)
{
    const int blk = blockIdx.x;
    const int t   = threadIdx.x;
    if (blk < 256) {
        int tid = blk * 256 + t;
        int ho = tid >> 8, k = tid & 255;
        W2T[(ho << 8) + k] = f2h_bits(W2[(k << 8) + ho]);
        if (tid < 256 * 64) {
            int h = tid >> 6, f = tid & 63;
            WeT[(h << 6) + f] = (f < FFE) ? f2h_bits(W1[(521 + f) * HH + h])
                                          : (unsigned short)0;
        }
    } else if (blk < 768) {
        int tid = (blk - 256) * 256 + t;      // 0..131071
        int hp = tid >> 8, f = tid & 255;     // h' 0..511, f 0..255
        int src = (((hp >> 8) << 8) + f) * HH + (hp & 255);
        W1jiT[(hp << 8) + f] = f2h_bits(W1[src]);
    } else {
        int b = blk - 768;                    // 0..15
        float acc = b1[t];
        #pragma unroll
        for (int l = 0; l < LLG; ++l)
            acc = fmaf(graph[b * LLG + l], W1[(2 * HH + l) * HH + t], acc);
        pg[(b << 8) + t] = acc;
    }
}

// ---------------------------------------------------------------------------
// Kernel 2: pj/base via MFMA. Grid 64 = (b, r-quarter). 4 waves.
//   D[h'(512), r(32)] = sum_f W1jiT[h'][f] * node[b][r0+r][f]   (K=256)
//   wave w owns h'-slice [w*128, w*128+128): w<2 -> pj, w>=2 -> base(+pg).
// ---------------------------------------------------------------------------
__global__ __launch_bounds__(256) void pre_pjbase_mfma(
    const float* __restrict__ node, const unsigned short* __restrict__ W1jiT,
    const float* __restrict__ pg,
    float* __restrict__ pj, float* __restrict__ base)
{
    __shared__ unsigned char nls[32 * 512];   // 16 KB: node[r][f] f16, swizzled
    const int tid = threadIdx.x;
    const int w    = tid >> 6;
    const int lane = tid & 63;
    const int q    = lane >> 4;
    const int c    = lane & 15;
    const int b  = blockIdx.x >> 2;
    const int r0 = (blockIdx.x & 3) << 5;
    const unsigned ck = (unsigned)(c & 7) << 4;

    // stage node rows r0..r0+32 (32x256 f32 -> f16), swizzled rows of 512 B
    const float* nb = node + (((size_t)b << 7) + r0) * HH;
    #pragma unroll
    for (int p = 0; p < 8; ++p) {
        const int e4 = (p << 8) + tid;        // float4 idx < 2048
        const int r  = e4 >> 6, f4 = e4 & 63;
        const f32x4 x = *reinterpret_cast<const f32x4*>(nb + (e4 << 2));
        unsigned int lo = __builtin_bit_cast(unsigned int,
                            __builtin_amdgcn_cvt_pkrtz(x[0], x[1]));
        unsigned int hi = __builtin_bit_cast(unsigned int,
                            __builtin_amdgcn_cvt_pkrtz(x[2], x[3]));
        const unsigned off = (unsigned)(r << 9) +
            (((unsigned)(f4 << 3)) ^ ((unsigned)(r & 7) << 4));
        *reinterpret_cast<uint2*>(&nls[off]) = make_uint2(lo, hi);
    }
    __syncthreads();

    const int wh = w << 7;                    // h'-slice base
    f32x4 acc[8][2];
    #pragma unroll
    for (int mt = 0; mt < 8; ++mt)
        #pragma unroll
        for (int nt = 0; nt < 2; ++nt) acc[mt][nt] = f32x4{0.f, 0.f, 0.f, 0.f};

    #pragma unroll 2
    for (int kk = 0; kk < 8; ++kk) {
        const unsigned kb = (unsigned)((kk << 6) + (q << 4));
        f16x8 bfr[2];
        #pragma unroll
        for (int nt = 0; nt < 2; ++nt) {
            const int r = (nt << 4) + c;
            bfr[nt] = *reinterpret_cast<const f16x8*>(
                &nls[(unsigned)(r << 9) + (kb ^ ck)]);
        }
        #pragma unroll
        for (int mt = 0; mt < 8; ++mt) {
            const f16x8 af = *reinterpret_cast<const f16x8*>(
                W1jiT + ((wh + (mt << 4) + c) << 8) + (kk << 5) + (q << 3));
            #pragma unroll
            for (int nt = 0; nt < 2; ++nt)
                acc[mt][nt] = __builtin_amdgcn_mfma_f32_16x16x32_f16(
                    af, bfr[nt], acc[mt][nt], 0, 0, 0);
        }
    }

    // epilogue: D rows h' = wh + mt*16 + q*4 + j ; cols r = nt*16 + c
    if (w < 2) {
        #pragma unroll
        for (int mt = 0; mt < 8; ++mt) {
            const int hb = wh + (mt << 4) + (q << 2);
            #pragma unroll
            for (int nt = 0; nt < 2; ++nt) {
                const int r = r0 + (nt << 4) + c;
                *reinterpret_cast<f32x4*>(
                    pj + (((size_t)b << 7) + r) * HH + hb) = acc[mt][nt];
            }
        }
    } else {
        #pragma unroll
        for (int mt = 0; mt < 8; ++mt) {
            const int hb = wh - 256 + (mt << 4) + (q << 2);
            const f32x4 pgv = *reinterpret_cast<const f32x4*>(
                pg + (b << 8) + hb);
            #pragma unroll
            for (int nt = 0; nt < 2; ++nt) {
                const int r = r0 + (nt << 4) + c;
                *reinterpret_cast<f32x4*>(
                    base + (((size_t)b << 7) + r) * HH + hb) = acc[mt][nt] + pgv;
            }
        }
    }
}

// ---------------------------------------------------------------------------
// Kernel 3: fused main — R5 structure + T1 XCD-chunked swizzle (best: 92 us).
// 8 structural variants (R4,R6,R7,R9,R10,R13,R15) all regressed; R8 neutral.
// Register-occupancy trade is closed: 124 unified regs/16 waves = 92 us;
// capping to 85 regs/24 waves spills 389 MB = 242 us (R15). Do not touch.
// ---------------------------------------------------------------------------
__global__ __launch_bounds__(512, 4) void fused_msg(
    const float* __restrict__ edge, const float* __restrict__ pj,
    const float* __restrict__ base, const unsigned short* __restrict__ W2T,
    const unsigned short* __restrict__ WeT, const float* __restrict__ b2,
    float* __restrict__ out)
{
    __shared__ unsigned char h1s[NN * HH * 2];   // 64 KB: h1[j][h] f16, swizzled
    __shared__ unsigned char efs[NN * 64 * 2];   // 16 KB: edge[j][f] f16, padded+swizzled
    const int tid  = threadIdx.x;
    const int w    = tid >> 6;         // wave 0..7
    const int lane = tid & 63;
    const int q    = lane >> 4;        // quad 0..3
    const int c    = lane & 15;
    // T1: XCD-chunked swizzle (2048 blocks, 8 XCDs, 2048%8==0 -> bijective)
    const int g    = blockIdx.x;
    const int bi   = ((g & 7) << 8) + (g >> 3);   // b*128 + i
    const int b    = bi >> 7;

    const float* eb = edge + (size_t)bi * (NN * FFE);

    // ---- stage edge block -> f16 LDS, row-padded to 64 f16, XOR-swizzled ----
    #pragma unroll
    for (int p = 0; p < 3; ++p) {
        const int e4 = p * 512 + tid;            // float4 index, < 1536
        const int j  = e4 / 12;                  // 12 float4 per 48-float row
        const int f4 = e4 - j * 12;              // 0..11
        const f32x4 x = *reinterpret_cast<const f32x4*>(eb + (e4 << 2));
        unsigned int lo = __builtin_bit_cast(unsigned int,
                            __builtin_amdgcn_cvt_pkrtz(x[0], x[1]));
        unsigned int hi = __builtin_bit_cast(unsigned int,
                            __builtin_amdgcn_cvt_pkrtz(x[2], x[3]));
        const unsigned int off = (unsigned)(j << 7) +
            (((unsigned)(f4 << 3)) ^ ((unsigned)(j & 7) << 4));
        *reinterpret_cast<uint2*>(&efs[off]) = make_uint2(lo, hi);
    }
    {   // zero-fill padded f in [48,64)
        const int j = tid >> 2, gg = tid & 3;
        const unsigned int off = (unsigned)(j << 7) +
            (((unsigned)(96 + (gg << 3))) ^ ((unsigned)(j & 7) << 4));
        *reinterpret_cast<uint2*>(&efs[off]) = make_uint2(0u, 0u);
    }
    __syncthreads();

    // ------------------ GEMM1: D1[h(32), j(128)] ------------------
    f32x4 acc1[2][8];
    #pragma unroll
    for (int mt = 0; mt < 2; ++mt)
        #pragma unroll
        for (int nt = 0; nt < 8; ++nt) acc1[mt][nt] = f32x4{0.f, 0.f, 0.f, 0.f};

    #pragma unroll
    for (int kk = 0; kk < 2; ++kk) {
        const int koff = (kk << 5) + (q << 3);   // f16-units f offset
        const int fb   = koff << 1;              // byte offset in efs row
        f16x8 af[2];
        #pragma unroll
        for (int mt = 0; mt < 2; ++mt) {
            const int row = (w << 5) + (mt << 4) + c;       // h
            af[mt] = *reinterpret_cast<const f16x8*>(WeT + (row << 6) + koff);
        }
        #pragma unroll
        for (int nt = 0; nt < 8; ++nt) {
            const int j = (nt << 4) + c;
            const f16x8 bf = *reinterpret_cast<const f16x8*>(
                &efs[(unsigned)(j << 7) +
                     (((unsigned)fb) ^ ((unsigned)(j & 7) << 4))]);
            #pragma unroll
            for (int mt = 0; mt < 2; ++mt)
                acc1[mt][nt] = __builtin_amdgcn_mfma_f32_16x16x32_f16(
                    af[mt], bf, acc1[mt][nt], 0, 0, 0);
        }
    }

    // epilogue 1: z1 -> silu -> f16 -> h1s (swizzle: byte ^= (j&7)<<4)
    #pragma unroll
    for (int mt = 0; mt < 2; ++mt) {
        const int h0 = (w << 5) + (mt << 4) + (q << 2);
        const f32x4 bb = *reinterpret_cast<const f32x4*>(
            base + ((size_t)bi << 8) + h0);
        #pragma unroll
        for (int nt = 0; nt < 8; ++nt) {
            const int jc = (nt << 4) + c;
            const f32x4 pjv = *reinterpret_cast<const f32x4*>(
                pj + (((size_t)b << 7) + jc) * HH + h0);
            float s0 = fast_silu(acc1[mt][nt][0] + bb[0] + pjv[0]);
            float s1 = fast_silu(acc1[mt][nt][1] + bb[1] + pjv[1]);
            float s2 = fast_silu(acc1[mt][nt][2] + bb[2] + pjv[2]);
            float s3 = fast_silu(acc1[mt][nt][3] + bb[3] + pjv[3]);
            unsigned int lo = __builtin_bit_cast(unsigned int,
                                __builtin_amdgcn_cvt_pkrtz(s0, s1));
            unsigned int hi = __builtin_bit_cast(unsigned int,
                                __builtin_amdgcn_cvt_pkrtz(s2, s3));
            const unsigned int off = (unsigned)(jc << 9) +
                (((unsigned)(h0 << 1)) ^ ((unsigned)(jc & 7) << 4));
            *reinterpret_cast<uint2*>(&h1s[off]) = make_uint2(lo, hi);
        }
    }
    __syncthreads();

    // ------------------ GEMM2: D2[jc(128), ho(32)] ------------------
    f32x4 acc2[8][2];
    #pragma unroll
    for (int mt = 0; mt < 8; ++mt)
        #pragma unroll
        for (int nt = 0; nt < 2; ++nt) acc2[mt][nt] = f32x4{0.f, 0.f, 0.f, 0.f};

    #pragma unroll 2
    for (int kk = 0; kk < 8; ++kk) {
        const int kb = (kk << 6) + (q << 4);     // byte offset of k-slice
        f16x8 bw[2];
        #pragma unroll
        for (int nt = 0; nt < 2; ++nt) {
            const int ho = (w << 5) + (nt << 4) + c;
            bw[nt] = *reinterpret_cast<const f16x8*>(
                W2T + (ho << 8) + (kk << 5) + (q << 3));
        }
        #pragma unroll
        for (int gg = 0; gg < 2; ++gg) {
            f16x8 a2[4];
            #pragma unroll
            for (int m = 0; m < 4; ++m) {
                const int jc = ((gg << 2) + m) * 16 + c;
                const unsigned int off = (unsigned)(jc << 9) +
                    (((unsigned)kb) ^ ((unsigned)(jc & 7) << 4));
                a2[m] = *reinterpret_cast<const f16x8*>(&h1s[off]);
            }
            #pragma unroll
            for (int m = 0; m < 4; ++m)
                #pragma unroll
                for (int nt = 0; nt < 2; ++nt)
                    acc2[(gg << 2) + m][nt] = __builtin_amdgcn_mfma_f32_16x16x32_f16(
                        a2[m], bw[nt], acc2[(gg << 2) + m][nt], 0, 0, 0);
        }
    }

    // epilogue 2: silu + j-sum, butterfly across quads, store
    float b2v[2];
    #pragma unroll
    for (int nt = 0; nt < 2; ++nt) b2v[nt] = b2[(w << 5) + (nt << 4) + c];

    float s[2] = {0.f, 0.f};
    #pragma unroll
    for (int nt = 0; nt < 2; ++nt)
        #pragma unroll
        for (int mt = 0; mt < 8; ++mt)
            #pragma unroll
            for (int r = 0; r < 4; ++r)
                s[nt] += fast_silu(acc2[mt][nt][r] + b2v[nt]);

    #pragma unroll
    for (int nt = 0; nt < 2; ++nt) {
        s[nt] += __shfl_xor(s[nt], 16);
        s[nt] += __shfl_xor(s[nt], 32);
    }
    if (q < 2)
        out[((size_t)bi << 8) + (w << 5) + (q << 4) + c] = s[q] * 0.0078125f;
}

// ---------------------------------------------------------------------------
extern "C" void kernel_launch(void* const* d_in, const int* in_sizes, int n_in,
                              void* d_out, int out_size, void* d_ws, size_t ws_size,
                              hipStream_t stream)
{
    const float* node  = (const float*)d_in[0];
    const float* edge  = (const float*)d_in[1];
    const float* graph = (const float*)d_in[2];
    const float* W1    = (const float*)d_in[3];
    const float* b1    = (const float*)d_in[4];
    const float* W2    = (const float*)d_in[5];
    const float* b2    = (const float*)d_in[6];
    float* out = (float*)d_out;

    char* ws = (char*)d_ws;
    unsigned short* W2T   = (unsigned short*)ws;               // 131072 B
    unsigned short* WeT   = (unsigned short*)(ws + 131072);    //  32768 B
    unsigned short* W1jiT = (unsigned short*)(ws + 163840);    // 262144 B
    float* pg   = (float*)(ws + 425984);                       //  16384 B
    float* pj   = (float*)(ws + 442368);                       // 2 MB
    float* base = (float*)(ws + 442368 + 2097152);             // 2 MB

    pre_w          <<<784, 256, 0, stream>>>(W1, W2, graph, b1, W2T, WeT, W1jiT, pg);
    pre_pjbase_mfma<<< 64, 256, 0, stream>>>(node, W1jiT, pg, pj, base);
    fused_msg      <<<BSZ * NN, 512, 0, stream>>>(edge, pj, base, W2T, WeT, b2, out);
}